// Round 1
// baseline (2113.722 us; speedup 1.0000x reference)
//
#include <hip/hip_runtime.h>
#include <stdint.h>

#define Bd 4
#define Nn 48
#define Mm 48
#define Hh 192
#define Ww 640
#define HW (Hh*Ww)          // 122880 pixels per mask
#define WORDS (HW/64)       // 1920 uint64 words per mask

// ---------------------------------------------------------------------------
// K1: pack fp32 binary masks into uint64 bitmasks, fused per-mask popcount sum
// One thread per pixel; each 64-lane wave produces one word via __ballot.
// ---------------------------------------------------------------------------
__global__ void pack_kernel(const float* __restrict__ a, const float* __restrict__ b,
                            uint64_t* __restrict__ packA, uint64_t* __restrict__ packB,
                            unsigned int* __restrict__ saInt, unsigned int* __restrict__ sbInt) {
    const long long NA = (long long)Bd * Nn * HW;   // multiple of 256 -> no wave straddles
    long long idx = (long long)blockIdx.x * blockDim.x + threadIdx.x;
    const float* src; uint64_t* dst; unsigned int* cnt; long long rel;
    if (idx < NA) { src = a; dst = packA; cnt = saInt; rel = idx; }
    else          { src = b; dst = packB; cnt = sbInt; rel = idx - NA; }
    bool pred = src[rel] > 0.0f;
    uint64_t word = __ballot(pred);
    if ((threadIdx.x & 63) == 0) {
        dst[rel >> 6] = word;
        atomicAdd(&cnt[(int)(rel / HW)], (unsigned int)__popcll(word));
    }
}

// ---------------------------------------------------------------------------
// K2: one wave per (b,n,m) pair. inter = sum popcount(A&B); q-test exactly as
// the float32 reference; set bit m of qmask[b][n] when qualifying.
// ---------------------------------------------------------------------------
__global__ void pair_kernel(const uint64_t* __restrict__ packA, const uint64_t* __restrict__ packB,
                            const unsigned int* __restrict__ saInt, const unsigned int* __restrict__ sbInt,
                            unsigned long long* __restrict__ qmask) {
    int wave = blockIdx.x * (blockDim.x >> 6) + (threadIdx.x >> 6);
    int lane = threadIdx.x & 63;
    int bb = wave / (Nn * Mm);
    int nm = wave % (Nn * Mm);
    int n = nm / Mm, m = nm % Mm;
    const uint64_t* A  = packA + (size_t)(bb * Nn + n) * WORDS;
    const uint64_t* Bp = packB + (size_t)(bb * Mm + m) * WORDS;
    unsigned int s = 0;
    #pragma unroll 5
    for (int w = lane; w < WORDS; w += 64)
        s += (unsigned int)__popcll(A[w] & Bp[w]);
    #pragma unroll
    for (int off = 32; off; off >>= 1) s += __shfl_down(s, off);
    if (lane == 0) {
        float inter = (float)s;
        float un = (float)saInt[bb * Nn + n] + (float)sbInt[bb * Mm + m] - inter;
        if (inter / fmaxf(un, 1.0f) > 0.8f)
            atomicOr(&qmask[bb * Nn + n], 1ull << m);
    }
}

// ---------------------------------------------------------------------------
// K3: per output word, OR of (a_n ^ b_m) over qualifying (n,m) pairs.
// ---------------------------------------------------------------------------
__global__ void words_kernel(const uint64_t* __restrict__ packA, const uint64_t* __restrict__ packB,
                             const unsigned long long* __restrict__ qmask,
                             uint64_t* __restrict__ zwords) {
    int i = blockIdx.x * blockDim.x + threadIdx.x;
    if (i >= Bd * WORDS) return;
    int bb = i / WORDS, w = i % WORDS;
    uint64_t acc = 0;
    for (int n = 0; n < Nn; ++n) {
        unsigned long long qm = qmask[bb * Nn + n];
        if (!qm) continue;
        uint64_t aw = packA[(size_t)(bb * Nn + n) * WORDS + w];
        while (qm) {
            int m = __ffsll((long long)qm) - 1;
            qm &= qm - 1;
            acc |= aw ^ packB[(size_t)(bb * Mm + m) * WORDS + w];
        }
        if (acc == ~0ull) break;   // word fully covered, nothing more can change
    }
    zwords[i] = acc;
}

// ---------------------------------------------------------------------------
// K4: expand bits to floats: bit set -> 0.0f (occluded), else 1.0f
// ---------------------------------------------------------------------------
__global__ void expand_kernel(const uint64_t* __restrict__ zwords, float* __restrict__ out) {
    int i = blockIdx.x * blockDim.x + threadIdx.x;
    if (i >= Bd * HW) return;
    uint64_t w = zwords[i >> 6];
    out[i] = ((w >> (i & 63)) & 1) ? 0.0f : 1.0f;
}

extern "C" void kernel_launch(void* const* d_in, const int* in_sizes, int n_in,
                              void* d_out, int out_size, void* d_ws, size_t ws_size,
                              hipStream_t stream) {
    const float* a = (const float*)d_in[0];   // stereo_warped_target  [B,N,H,W]
    const float* b = (const float*)d_in[1];   // temporal_warped_target [B,M,H,W]
    float* out = (float*)d_out;               // [B,1,H,W]

    uint8_t* ws = (uint8_t*)d_ws;
    const size_t szPack = (size_t)Bd * Nn * WORDS * sizeof(uint64_t);  // 2.95 MB (N==M)
    uint64_t* packA = (uint64_t*)(ws);
    uint64_t* packB = (uint64_t*)(ws + szPack);
    unsigned int* saInt = (unsigned int*)(ws + 2 * szPack);
    unsigned int* sbInt = saInt + Bd * Nn;
    unsigned long long* qmask = (unsigned long long*)(ws + 2 * szPack + (size_t)Bd * (Nn + Mm) * 4);
    uint64_t* zwords = (uint64_t*)((uint8_t*)qmask + (size_t)Bd * Nn * 8);

    // zero the atomically-accumulated arrays (counters + qmask) in one memset
    hipMemsetAsync(saInt, 0, (size_t)Bd * (Nn + Mm) * 4 + (size_t)Bd * Nn * 8, stream);

    // K1: pack + popcount sums
    {
        long long total = (long long)Bd * (Nn + Mm) * HW;   // 47,185,920
        int blocks = (int)(total / 256);
        pack_kernel<<<blocks, 256, 0, stream>>>(a, b, packA, packB, saInt, sbInt);
    }
    // K2: pairwise IoU -> qmask
    {
        int pairs = Bd * Nn * Mm;          // 9216 waves
        int blocks = pairs / 4;            // 4 waves per 256-thread block
        pair_kernel<<<blocks, 256, 0, stream>>>(packA, packB, saInt, sbInt, qmask);
    }
    // K3: zero-word computation
    {
        int total = Bd * WORDS;            // 7680
        int blocks = (total + 255) / 256;
        words_kernel<<<blocks, 256, 0, stream>>>(packA, packB, qmask, zwords);
    }
    // K4: expand to float output
    {
        int total = Bd * HW;               // 491,520
        int blocks = (total + 255) / 256;
        expand_kernel<<<blocks, 256, 0, stream>>>(zwords, out);
    }
}

// Round 2
// 92.417 us; speedup vs baseline: 22.8716x; 22.8716x over previous
//
#include <hip/hip_runtime.h>
#include <stdint.h>

#define Bd 4
#define Nn 48
#define Mm 48
#define Hh 192
#define Ww 640
#define HW (Hh*Ww)          // 122880 pixels per mask
#define WORDS (HW/64)       // 1920 uint64 words per mask
#define PIX_PER_BLOCK 4096  // 256 threads x 16 pixels; HW % 4096 == 0 -> block never straddles masks

// ---------------------------------------------------------------------------
// K1: pack fp32 binary masks into uint64 bitmasks + fused per-mask popcount.
// Thread: 16 pixels via 4x float4 -> 16-bit mask -> LDS.
// Lanes 0..63: assemble uint64 from LDS (little-endian ushort order == bit
// order), coalesced 8B store, popcount + wave-reduce, 1 atomicAdd per block.
// ---------------------------------------------------------------------------
__global__ void pack_kernel(const float* __restrict__ a, const float* __restrict__ b,
                            uint64_t* __restrict__ packA, uint64_t* __restrict__ packB,
                            unsigned int* __restrict__ saInt, unsigned int* __restrict__ sbInt) {
    __shared__ ushort smem[256];
    const int blocksA = (Bd * Nn * HW) / PIX_PER_BLOCK;   // 5760
    long long pixBase;
    const float* src; uint64_t* dst; unsigned int* cnt;
    if (blockIdx.x < blocksA) {
        src = a; dst = packA; cnt = saInt;
        pixBase = (long long)blockIdx.x * PIX_PER_BLOCK;
    } else {
        src = b; dst = packB; cnt = sbInt;
        pixBase = (long long)(blockIdx.x - blocksA) * PIX_PER_BLOCK;
    }
    const float* p = src + pixBase + (long long)threadIdx.x * 16;
    unsigned int bits = 0;
    #pragma unroll
    for (int c = 0; c < 4; ++c) {
        float4 v = *reinterpret_cast<const float4*>(p + c * 4);
        bits |= (v.x > 0.0f ? 1u : 0u) << (c * 4 + 0);
        bits |= (v.y > 0.0f ? 1u : 0u) << (c * 4 + 1);
        bits |= (v.z > 0.0f ? 1u : 0u) << (c * 4 + 2);
        bits |= (v.w > 0.0f ? 1u : 0u) << (c * 4 + 3);
    }
    smem[threadIdx.x] = (ushort)bits;
    __syncthreads();
    if (threadIdx.x < 64) {
        uint64_t word = reinterpret_cast<const uint64_t*>(smem)[threadIdx.x];
        dst[(pixBase >> 6) + threadIdx.x] = word;
        unsigned int s = (unsigned int)__popcll(word);
        #pragma unroll
        for (int off = 32; off; off >>= 1) s += __shfl_down(s, off);
        if (threadIdx.x == 0)
            atomicAdd(&cnt[(int)(pixBase / HW)], s);   // 30 adds per counter total
    }
}

// ---------------------------------------------------------------------------
// K2: one wave per (b,n,m) pair. inter = sum popcount(A&B); q-test exactly as
// the float32 reference; set bit m of qmask[b][n] when qualifying.
// ---------------------------------------------------------------------------
__global__ void pair_kernel(const uint64_t* __restrict__ packA, const uint64_t* __restrict__ packB,
                            const unsigned int* __restrict__ saInt, const unsigned int* __restrict__ sbInt,
                            unsigned long long* __restrict__ qmask) {
    int wave = blockIdx.x * (blockDim.x >> 6) + (threadIdx.x >> 6);
    int lane = threadIdx.x & 63;
    int bb = wave / (Nn * Mm);
    int nm = wave % (Nn * Mm);
    int n = nm / Mm, m = nm % Mm;
    const uint64_t* A  = packA + (size_t)(bb * Nn + n) * WORDS;
    const uint64_t* Bp = packB + (size_t)(bb * Mm + m) * WORDS;
    unsigned int s = 0;
    #pragma unroll 5
    for (int w = lane; w < WORDS; w += 64)
        s += (unsigned int)__popcll(A[w] & Bp[w]);
    #pragma unroll
    for (int off = 32; off; off >>= 1) s += __shfl_down(s, off);
    if (lane == 0) {
        float inter = (float)s;
        float un = (float)saInt[bb * Nn + n] + (float)sbInt[bb * Mm + m] - inter;
        if (inter / fmaxf(un, 1.0f) > 0.8f)
            atomicOr(&qmask[bb * Nn + n], 1ull << m);
    }
}

// ---------------------------------------------------------------------------
// K3: per output word, OR of (a_n ^ b_m) over qualifying (n,m) pairs.
// ---------------------------------------------------------------------------
__global__ void words_kernel(const uint64_t* __restrict__ packA, const uint64_t* __restrict__ packB,
                             const unsigned long long* __restrict__ qmask,
                             uint64_t* __restrict__ zwords) {
    int i = blockIdx.x * blockDim.x + threadIdx.x;
    if (i >= Bd * WORDS) return;
    int bb = i / WORDS, w = i % WORDS;
    uint64_t acc = 0;
    for (int n = 0; n < Nn; ++n) {
        unsigned long long qm = qmask[bb * Nn + n];
        if (!qm) continue;
        uint64_t aw = packA[(size_t)(bb * Nn + n) * WORDS + w];
        while (qm) {
            int m = __ffsll((long long)qm) - 1;
            qm &= qm - 1;
            acc |= aw ^ packB[(size_t)(bb * Mm + m) * WORDS + w];
        }
        if (acc == ~0ull) break;   // word fully covered, nothing more can change
    }
    zwords[i] = acc;
}

// ---------------------------------------------------------------------------
// K4: expand bits to floats: bit set -> 0.0f (occluded), else 1.0f
// ---------------------------------------------------------------------------
__global__ void expand_kernel(const uint64_t* __restrict__ zwords, float* __restrict__ out) {
    int i = blockIdx.x * blockDim.x + threadIdx.x;
    if (i >= Bd * HW) return;
    uint64_t w = zwords[i >> 6];
    out[i] = ((w >> (i & 63)) & 1) ? 0.0f : 1.0f;
}

extern "C" void kernel_launch(void* const* d_in, const int* in_sizes, int n_in,
                              void* d_out, int out_size, void* d_ws, size_t ws_size,
                              hipStream_t stream) {
    const float* a = (const float*)d_in[0];   // stereo_warped_target  [B,N,H,W]
    const float* b = (const float*)d_in[1];   // temporal_warped_target [B,M,H,W]
    float* out = (float*)d_out;               // [B,1,H,W]

    uint8_t* ws = (uint8_t*)d_ws;
    const size_t szPack = (size_t)Bd * Nn * WORDS * sizeof(uint64_t);  // 2.95 MB (N==M)
    uint64_t* packA = (uint64_t*)(ws);
    uint64_t* packB = (uint64_t*)(ws + szPack);
    unsigned int* saInt = (unsigned int*)(ws + 2 * szPack);
    unsigned int* sbInt = saInt + Bd * Nn;
    unsigned long long* qmask = (unsigned long long*)(ws + 2 * szPack + (size_t)Bd * (Nn + Mm) * 4);
    uint64_t* zwords = (uint64_t*)((uint8_t*)qmask + (size_t)Bd * Nn * 8);

    // zero the atomically-accumulated arrays (counters + qmask) in one memset
    hipMemsetAsync(saInt, 0, (size_t)Bd * (Nn + Mm) * 4 + (size_t)Bd * Nn * 8, stream);

    // K1: pack + popcount sums (one atomic per block)
    {
        int blocks = (Bd * (Nn + Mm) * HW) / PIX_PER_BLOCK;   // 11520
        pack_kernel<<<blocks, 256, 0, stream>>>(a, b, packA, packB, saInt, sbInt);
    }
    // K2: pairwise IoU -> qmask
    {
        int pairs = Bd * Nn * Mm;          // 9216 waves
        int blocks = pairs / 4;            // 4 waves per 256-thread block
        pair_kernel<<<blocks, 256, 0, stream>>>(packA, packB, saInt, sbInt, qmask);
    }
    // K3: zero-word computation
    {
        int total = Bd * WORDS;            // 7680
        int blocks = (total + 255) / 256;
        words_kernel<<<blocks, 256, 0, stream>>>(packA, packB, qmask, zwords);
    }
    // K4: expand to float output
    {
        int total = Bd * HW;               // 491,520
        int blocks = (total + 255) / 256;
        expand_kernel<<<blocks, 256, 0, stream>>>(zwords, out);
    }
}

// Round 3
// 92.302 us; speedup vs baseline: 22.9002x; 1.0013x over previous
//
#include <hip/hip_runtime.h>
#include <stdint.h>

#define Bd 4
#define Nn 48
#define Mm 48
#define Hh 192
#define Ww 640
#define HW (Hh*Ww)          // 122880 pixels per mask
#define WORDS (HW/64)       // 1920 uint64 words per mask
#define PIX_PER_BLOCK 4096  // 256 threads x 4 float4 = 4096 pixels; HW % 4096 == 0
#define ITERS 4             // float4 loads per thread

// ---------------------------------------------------------------------------
// K1: pack fp32 binary masks into uint64 bitmasks + fused per-mask popcount.
// Lane i loads float4 at base+i (16B/lane contiguous -> 100% per-instruction
// line utilization). Each float4 -> 4-bit nibble -> LDS (uint, padded idx).
// Threads 0..63 assemble one uint64 word each from 16 nibbles, store 512B
// contiguous, wave-reduce popcount, 1 atomicAdd per block.
// ---------------------------------------------------------------------------
__global__ void pack_kernel(const float* __restrict__ a, const float* __restrict__ b,
                            uint64_t* __restrict__ packA, uint64_t* __restrict__ packB,
                            unsigned int* __restrict__ saInt, unsigned int* __restrict__ sbInt) {
    __shared__ unsigned int nib[ITERS * 256 + (ITERS * 256) / 16];  // padded: idx + idx/16
    const int blocksA = (Bd * Nn * HW) / PIX_PER_BLOCK;   // 5760
    long long pixBase;
    const float* src; uint64_t* dst; unsigned int* cnt;
    if (blockIdx.x < blocksA) {
        src = a; dst = packA; cnt = saInt;
        pixBase = (long long)blockIdx.x * PIX_PER_BLOCK;
    } else {
        src = b; dst = packB; cnt = sbInt;
        pixBase = (long long)(blockIdx.x - blocksA) * PIX_PER_BLOCK;
    }
    const float4* s4 = reinterpret_cast<const float4*>(src) + (pixBase >> 2);
    const int t = threadIdx.x;
    #pragma unroll
    for (int c = 0; c < ITERS; ++c) {
        float4 v = s4[c * 256 + t];                       // fully coalesced 16B/lane
        unsigned int n = (v.x > 0.0f ? 1u : 0u)
                       | (v.y > 0.0f ? 2u : 0u)
                       | (v.z > 0.0f ? 4u : 0u)
                       | (v.w > 0.0f ? 8u : 0u);
        int idx = c * 256 + t;
        nib[idx + (idx >> 4)] = n;                        // padded store, conflict-free
    }
    __syncthreads();
    if (t < 64) {
        // word t <- nibbles [16t, 16t+16) at padded addr 17t+k (banks distinct mod 32)
        uint64_t word = 0;
        #pragma unroll
        for (int k = 0; k < 16; ++k)
            word |= (uint64_t)nib[17 * t + k] << (4 * k);
        dst[(pixBase >> 6) + t] = word;                   // 512B contiguous per block
        unsigned int s = (unsigned int)__popcll(word);
        #pragma unroll
        for (int off = 32; off; off >>= 1) s += __shfl_down(s, off);
        if (t == 0)
            atomicAdd(&cnt[(int)(pixBase / HW)], s);      // 30 adds per counter total
    }
}

// ---------------------------------------------------------------------------
// K2: one wave per (b,n,m) pair. inter = sum popcount(A&B); q-test exactly as
// the float32 reference; set bit m of qmask[b][n] when qualifying.
// ---------------------------------------------------------------------------
__global__ void pair_kernel(const uint64_t* __restrict__ packA, const uint64_t* __restrict__ packB,
                            const unsigned int* __restrict__ saInt, const unsigned int* __restrict__ sbInt,
                            unsigned long long* __restrict__ qmask) {
    int wave = blockIdx.x * (blockDim.x >> 6) + (threadIdx.x >> 6);
    int lane = threadIdx.x & 63;
    int bb = wave / (Nn * Mm);
    int nm = wave % (Nn * Mm);
    int n = nm / Mm, m = nm % Mm;
    const uint64_t* A  = packA + (size_t)(bb * Nn + n) * WORDS;
    const uint64_t* Bp = packB + (size_t)(bb * Mm + m) * WORDS;
    unsigned int s = 0;
    #pragma unroll 5
    for (int w = lane; w < WORDS; w += 64)
        s += (unsigned int)__popcll(A[w] & Bp[w]);
    #pragma unroll
    for (int off = 32; off; off >>= 1) s += __shfl_down(s, off);
    if (lane == 0) {
        float inter = (float)s;
        float un = (float)saInt[bb * Nn + n] + (float)sbInt[bb * Mm + m] - inter;
        if (inter / fmaxf(un, 1.0f) > 0.8f)
            atomicOr(&qmask[bb * Nn + n], 1ull << m);
    }
}

// ---------------------------------------------------------------------------
// K3+K4 fused: per word, OR of (a_n ^ b_m) over qualifying pairs -> LDS ->
// coalesced float4 expansion to the output.
// Block = 256 threads = 256 words = 16384 pixels. Output is flat [B*HW], and
// (b*WORDS+w)*64+j == global pixel index, so no mask-straddle concerns.
// ---------------------------------------------------------------------------
__global__ void words_expand_kernel(const uint64_t* __restrict__ packA,
                                    const uint64_t* __restrict__ packB,
                                    const unsigned long long* __restrict__ qmask,
                                    float* __restrict__ out) {
    __shared__ uint64_t sw[256];
    const int t = threadIdx.x;
    const int i = blockIdx.x * 256 + t;       // word index in [0, Bd*WORDS)
    const int bb = i / WORDS, w = i % WORDS;
    uint64_t acc = 0;
    for (int n = 0; n < Nn; ++n) {
        unsigned long long qm = qmask[bb * Nn + n];
        if (!qm) continue;
        uint64_t aw = packA[(size_t)(bb * Nn + n) * WORDS + w];
        while (qm) {
            int m = __ffsll((long long)qm) - 1;
            qm &= qm - 1;
            acc |= aw ^ packB[(size_t)(bb * Mm + m) * WORDS + w];
        }
        if (acc == ~0ull) break;              // word fully covered
    }
    sw[t] = acc;
    __syncthreads();
    float4* out4 = reinterpret_cast<float4*>(out) + (size_t)blockIdx.x * 4096;
    #pragma unroll
    for (int k = 0; k < 16; ++k) {
        int p0 = k * 1024 + 4 * t;            // first of this thread's 4 pixels
        uint64_t wv = sw[p0 >> 6];            // broadcast within 16-lane groups
        unsigned int bits = (unsigned int)(wv >> (p0 & 63)) & 0xFu;
        float4 f;
        f.x = (bits & 1u) ? 0.0f : 1.0f;
        f.y = (bits & 2u) ? 0.0f : 1.0f;
        f.z = (bits & 4u) ? 0.0f : 1.0f;
        f.w = (bits & 8u) ? 0.0f : 1.0f;
        out4[k * 256 + t] = f;                // 4KB contiguous per instruction
    }
}

extern "C" void kernel_launch(void* const* d_in, const int* in_sizes, int n_in,
                              void* d_out, int out_size, void* d_ws, size_t ws_size,
                              hipStream_t stream) {
    const float* a = (const float*)d_in[0];   // stereo_warped_target  [B,N,H,W]
    const float* b = (const float*)d_in[1];   // temporal_warped_target [B,M,H,W]
    float* out = (float*)d_out;               // [B,1,H,W]

    uint8_t* ws = (uint8_t*)d_ws;
    const size_t szPack = (size_t)Bd * Nn * WORDS * sizeof(uint64_t);  // 2.95 MB (N==M)
    uint64_t* packA = (uint64_t*)(ws);
    uint64_t* packB = (uint64_t*)(ws + szPack);
    unsigned int* saInt = (unsigned int*)(ws + 2 * szPack);
    unsigned int* sbInt = saInt + Bd * Nn;
    unsigned long long* qmask = (unsigned long long*)(ws + 2 * szPack + (size_t)Bd * (Nn + Mm) * 4);

    // zero the atomically-accumulated arrays (counters + qmask) in one memset
    hipMemsetAsync(saInt, 0, (size_t)Bd * (Nn + Mm) * 4 + (size_t)Bd * Nn * 8, stream);

    // K1: pack + popcount sums (one atomic per block)
    {
        int blocks = (Bd * (Nn + Mm) * HW) / PIX_PER_BLOCK;   // 11520
        pack_kernel<<<blocks, 256, 0, stream>>>(a, b, packA, packB, saInt, sbInt);
    }
    // K2: pairwise IoU -> qmask
    {
        int pairs = Bd * Nn * Mm;          // 9216 waves
        int blocks = pairs / 4;            // 4 waves per 256-thread block
        pair_kernel<<<blocks, 256, 0, stream>>>(packA, packB, saInt, sbInt, qmask);
    }
    // K3+K4 fused: zero-words + float expansion
    {
        int blocks = (Bd * WORDS) / 256;   // 30
        words_expand_kernel<<<blocks, 256, 0, stream>>>(packA, packB, qmask, out);
    }
}